// Round 6
// baseline (243.019 us; speedup 1.0000x reference)
//
#include <hip/hip_runtime.h>
#include <math.h>

#define NTOK 16384
#define DIM 2048
#define NEXP 64
#define KG 8               // K-split groups (cross-block)
#define NC 8               // chunks of 32 per K-group (8*8*32 = 2048)
#define WTOK 64            // tokens per wave (4 A-tiles share each W fragment)
#define BTOK 256           // tokens per block (4 waves)

// flat output offsets (return order)
#define OFF_W    0
#define OFF_I    32768
#define OFF_P    65536
#define OFF_ENT  1114112
#define OFF_CONF 1114113
#define OFF_UTIL 1114114

// workspace layout (floats): [0,196608) wsp (768KB), then partial logits
#define PLG_OFF  196608
#define PLG_STRIDE 1048576           // 16384*64 floats per K-group
#define WS_NEED_STRIDED (786432ull + 33554432ull)   // bytes: wsp + 8 partial planes

typedef short s16x8 __attribute__((ext_vector_type(8)));
typedef float f32x4 __attribute__((ext_vector_type(4)));

__device__ __forceinline__ unsigned short f2bf(float v) {
    unsigned u = __builtin_bit_cast(unsigned, v);
    u = u + 0x7FFFu + ((u >> 16) & 1u);          // RNE
    return (unsigned short)(u >> 16);
}
__device__ __forceinline__ float bf2f(unsigned short b) {
    return __builtin_bit_cast(float, (unsigned)b << 16);
}

// async 16B global->LDS (dest = wave-uniform base + lane*16, tracked by vmcnt)
__device__ __forceinline__ void gload16(const void* g, void* l) {
    __builtin_amdgcn_global_load_lds(
        (const __attribute__((address_space(1))) unsigned int*)g,
        (__attribute__((address_space(3))) unsigned int*)l, 16, 0, 0);
}

// Split W into 3 bf16 planes (hi/mid/lo), fragment-linear (verified):
// plane p, chunk c, ntile nt, lane l -> uint4 at wsp[p*16384 + c*256 + nt*64 + l]
// fragment element j: W[16nt + (l&15)][32c + 8*(l>>4) + j]
// Also zeroes the 66 stat accumulators.
__global__ void router_wsplit(const float* __restrict__ Wg, uint4* __restrict__ wsp,
                              float* __restrict__ out) {
    const int bid = blockIdx.x;
    const int tid = threadIdx.x;
    const int c   = bid >> 2;
    const int gt  = (bid & 3) * 64 + tid;   // 0..255 within chunk
    if (c == 0 && gt < 66) out[OFF_ENT + gt] = 0.0f;
    const int nt = gt >> 6, l = gt & 63;
    const int e  = 16 * nt + (l & 15);
    const int k0 = 32 * c + 8 * (l >> 4);
    const float* src = Wg + (size_t)e * DIM + k0;
    float4 a = *(const float4*)src;
    float4 b = *(const float4*)(src + 4);
    float v[8] = {a.x, a.y, a.z, a.w, b.x, b.y, b.z, b.w};
    unsigned short H[8], M[8], L[8];
    #pragma unroll
    for (int j = 0; j < 8; ++j) {
        H[j] = f2bf(v[j]);  float r = v[j] - bf2f(H[j]);
        M[j] = f2bf(r);     r = r - bf2f(M[j]);
        L[j] = f2bf(r);
    }
    uint4 ph, pm, pl;
    ph.x = H[0] | ((unsigned)H[1] << 16); ph.y = H[2] | ((unsigned)H[3] << 16);
    ph.z = H[4] | ((unsigned)H[5] << 16); ph.w = H[6] | ((unsigned)H[7] << 16);
    pm.x = M[0] | ((unsigned)M[1] << 16); pm.y = M[2] | ((unsigned)M[3] << 16);
    pm.z = M[4] | ((unsigned)M[5] << 16); pm.w = M[6] | ((unsigned)M[7] << 16);
    pl.x = L[0] | ((unsigned)L[1] << 16); pl.y = L[2] | ((unsigned)L[3] << 16);
    pl.z = L[4] | ((unsigned)L[5] << 16); pl.w = L[6] | ((unsigned)L[7] << 16);
    const int idx = c * 256 + gt;
    wsp[idx]         = ph;
    wsp[16384 + idx] = pm;
    wsp[32768 + idx] = pl;
}

__global__ void router_zero(float* __restrict__ p) {
    ((float4*)p)[blockIdx.x * 256 + threadIdx.x] = make_float4(0.f, 0.f, 0.f, 0.f);
}

// exact truncation split of 8 fp32 -> 3 bf16 frags (identical math to verified kernels)
#define CONVA3(a0_, a1_) {                                               \
    float xv[8];                                                         \
    xv[0]=a0_.x; xv[1]=a0_.y; xv[2]=a0_.z; xv[3]=a0_.w;                  \
    xv[4]=a1_.x; xv[5]=a1_.y; xv[6]=a1_.z; xv[7]=a1_.w;                  \
    _Pragma("unroll")                                                    \
    for (int j = 0; j < 8; ++j) {                                        \
        unsigned u_  = __builtin_bit_cast(unsigned, xv[j]);              \
        unsigned hb_ = u_ & 0xFFFF0000u;                                 \
        float    r_  = xv[j] - __builtin_bit_cast(float, hb_);           \
        unsigned mb_ = __builtin_bit_cast(unsigned, r_) & 0xFFFF0000u;   \
        float    r2_ = r_ - __builtin_bit_cast(float, mb_);              \
        unsigned lb_ = __builtin_bit_cast(unsigned, r2_);                \
        ah[j] = (short)(hb_ >> 16);                                      \
        am[j] = (short)(mb_ >> 16);                                      \
        al[j] = (short)(lb_ >> 16);                                      \
    } }

#define MF(A_, B_, C_) __builtin_amdgcn_mfma_f32_16x16x32_bf16(A_, B_, C_, 0, 0, 0)
#define BC(q_) __builtin_bit_cast(s16x8, q_)

// stage chunk c_ of this wave's 64 tokens into ring[wv][c_&1] (8 async 1KB ops).
// XOR swizzle applied on the GLOBAL source (LDS dest linear, rule #21): LDS
// 32B-granule slot s of token tau holds global granule s ^ (tau&3).
#define STAGE(c_) { _Pragma("unroll")                                    \
    for (int i_ = 0; i_ < 8; ++i_) {                                     \
        const int tau_ = 8 * i_ + (l >> 3);                              \
        const int gs_  = ((l & 7) >> 1) ^ (tau_ & 3);                    \
        gload16(xw + (size_t)tau_ * DIM + (c_) * 32 + gs_ * 8 + (l & 1) * 4, \
                &ring[wv][(c_) & 1][8 * i_][0]);                         \
    } }

// read A-frag for token-tile tt_ (0..3) from ring, convert to 3 bf16 frags
#define READA(tt_, c_) {                                                 \
    const int tau_ = (tt_) * 16 + tr;                                    \
    const int sl_  = qd ^ (tau_ & 3);                                    \
    const uint4* row_ = &ring[wv][(c_) & 1][tau_][0];                    \
    float4 a0_ = __builtin_bit_cast(float4, row_[2 * sl_]);              \
    float4 a1_ = __builtin_bit_cast(float4, row_[2 * sl_ + 1]);          \
    CONVA3(a0_, a1_);                                                    \
    }

// W regs: 12 uint4 = 4 ntiles x 3 planes for one chunk
#define LOADW12(W_, c_) { const int b_ = (kg * NC + (c_)) * 256 + l;     \
    W_[0] = wq[b_];          W_[1] = wq[b_ + 64];                        \
    W_[2] = wq[b_ + 128];    W_[3] = wq[b_ + 192];                       \
    W_[4] = wq[16384 + b_];       W_[5] = wq[16384 + b_ + 64];           \
    W_[6] = wq[16384 + b_ + 128]; W_[7] = wq[16384 + b_ + 192];          \
    W_[8] = wq[32768 + b_];       W_[9] = wq[32768 + b_ + 64];           \
    W_[10] = wq[32768 + b_ + 128]; W_[11] = wq[32768 + b_ + 192]; }

#define PR4(F_, W_, o_, Q0_, Q1_, Q2_, Q3_) {                            \
    Q0_ = MF(F_, BC(W_[(o_) + 0]), Q0_);                                 \
    Q1_ = MF(F_, BC(W_[(o_) + 1]), Q1_);                                 \
    Q2_ = MF(F_, BC(W_[(o_) + 2]), Q2_);                                 \
    Q3_ = MF(F_, BC(W_[(o_) + 3]), Q3_); }

// 24 MFMAs: 4 ntiles x 6 products {hh,mh,hm,mm,hl,lh} (verified per-acc order)
#define COMPUTE24(W_, Q0_, Q1_, Q2_, Q3_) {                              \
    PR4(ah, W_, 0, Q0_, Q1_, Q2_, Q3_);                                  \
    PR4(am, W_, 0, Q0_, Q1_, Q2_, Q3_);                                  \
    PR4(ah, W_, 4, Q0_, Q1_, Q2_, Q3_);                                  \
    PR4(am, W_, 4, Q0_, Q1_, Q2_, Q3_);                                  \
    PR4(ah, W_, 8, Q0_, Q1_, Q2_, Q3_);                                  \
    PR4(al, W_, 0, Q0_, Q1_, Q2_, Q3_); }

// one K-chunk: stage c+1 (other buffer), counted wait with EXPLICIT count N_:
// N_ = number of VMEM ops issued after stage(c_) at the wait point.
//   c<7: stage(c+1) = 8 ops newer  -> vmcnt(8) forces stage(c) complete.
//   c=7: nothing newer             -> vmcnt(0)  (fixes r5's tail hazard).
// Then 4 token-tiles x 24 MFMA sharing one W-chunk (4x W amortization),
// then reload the just-consumed W buffer (natural WAR order).
#define PHASE(c_, W_, N_) {                                              \
    if ((c_) + 1 < NC) STAGE((c_) + 1);                                  \
    asm volatile("s_waitcnt vmcnt(" #N_ ")" ::: "memory");               \
    __builtin_amdgcn_sched_barrier(0);                                   \
    READA(0, c_);                                                        \
    COMPUTE24(W_, q00, q01, q02, q03);                                   \
    READA(1, c_);                                                        \
    COMPUTE24(W_, q10, q11, q12, q13);                                   \
    READA(2, c_);                                                        \
    COMPUTE24(W_, q20, q21, q22, q23);                                   \
    READA(3, c_);                                                        \
    COMPUTE24(W_, q30, q31, q32, q33);                                   \
    if ((c_) + 2 < NC) LOADW12(W_, (c_) + 2);                            \
    }

// 256 threads = 4 independent waves (NO barriers anywhere in the kernel).
// wave = 64 tokens x 64 experts x K-slice 256. block = 256 tokens, one kg.
// grid = 64 token-blocks x 8 kg = 512 blocks -> 2 blocks/CU, 8 waves/CU.
template<bool STRIDED>
__global__ __launch_bounds__(256, 2) void router_main(
    const float* __restrict__ x, const uint4* __restrict__ wq,
    float* __restrict__ plg)
{
    // per-wave private x ring: [wave][buf][token][8 x 16B] = 64KB
    __shared__ __align__(16) uint4 ring[4][2][WTOK][8];

    const int tid = threadIdx.x;
    const int l   = tid & 63;
    const int wv  = tid >> 6;
    const int tr  = l & 15;                 // token row in tile
    const int qd  = l >> 4;                 // K-octet 0..3
    const int kg  = blockIdx.x & 7;         // K-group
    const int tb  = blockIdx.x >> 3;        // token-block 0..63
    const int t0w = tb * BTOK + wv * WTOK;  // this wave's first token

    const float* xw = x + (size_t)t0w * DIM + kg * (NC * 32);

    f32x4 q00 = (f32x4)(0.f), q01 = (f32x4)(0.f), q02 = (f32x4)(0.f), q03 = (f32x4)(0.f);
    f32x4 q10 = (f32x4)(0.f), q11 = (f32x4)(0.f), q12 = (f32x4)(0.f), q13 = (f32x4)(0.f);
    f32x4 q20 = (f32x4)(0.f), q21 = (f32x4)(0.f), q22 = (f32x4)(0.f), q23 = (f32x4)(0.f);
    f32x4 q30 = (f32x4)(0.f), q31 = (f32x4)(0.f), q32 = (f32x4)(0.f), q33 = (f32x4)(0.f);
    s16x8 ah, am, al;
    uint4 wA[12], wB[12];

    // prologue: stage chunk 0, 2 W chunks in registers
    STAGE(0);
    LOADW12(wA, 0); LOADW12(wB, 1);

    PHASE(0, wA, 8); PHASE(1, wB, 8); PHASE(2, wA, 8); PHASE(3, wB, 8);
    PHASE(4, wA, 8); PHASE(5, wB, 8); PHASE(6, wA, 8); PHASE(7, wB, 0);

    // write K-partials. C/D layout (verified): col = l&15 (expert-in-ntile),
    // row = 4*qd + r (token-in-tile)
    float* dst = STRIDED ? (plg + (size_t)kg * PLG_STRIDE) : plg;
#define STACC(acc_, tt_, nt_) { _Pragma("unroll")                        \
    for (int r = 0; r < 4; ++r) {                                        \
        int tok = t0w + (tt_) * 16 + 4 * qd + r;                         \
        int ex_ = (nt_) * 16 + tr;                                       \
        if constexpr (STRIDED) dst[(size_t)tok * 64 + ex_] = acc_[r];    \
        else atomicAdd(&dst[(size_t)tok * 64 + ex_], acc_[r]);           \
    } }
    STACC(q00, 0, 0); STACC(q01, 0, 1); STACC(q02, 0, 2); STACC(q03, 0, 3);
    STACC(q10, 1, 0); STACC(q11, 1, 1); STACC(q12, 1, 2); STACC(q13, 1, 3);
    STACC(q20, 2, 0); STACC(q21, 2, 1); STACC(q22, 2, 2); STACC(q23, 2, 3);
    STACC(q30, 3, 0); STACC(q31, 3, 1); STACC(q32, 3, 2); STACC(q33, 3, 3);
#undef STACC
}

// tie-aware top-2 merge (lowest index wins ties — matches serial ascending scan)
__device__ __forceinline__ void merge2(float& m1, int& i1, float& m2, int& i2,
                                       float om1, int oi1, float om2, int oi2) {
    bool of = (om1 > m1) || (om1 == m1 && oi1 < i1);
    float n1, n2; int j1, j2;
    if (of) {
        n1 = om1; j1 = oi1;
        bool s = (m1 > om2) || (m1 == om2 && i1 < oi2);
        n2 = s ? m1 : om2; j2 = s ? i1 : oi2;
    } else {
        n1 = m1; j1 = i1;
        bool s = (om1 > m2) || (om1 == m2 && oi1 < i2);
        n2 = s ? om1 : m2; j2 = s ? oi1 : i2;
    }
    m1 = n1; i1 = j1; m2 = n2; i2 = j2;
}

// reduce K-partials (fixed ascending order -> deterministic, r4 association)
// + top-2 + softmax + stats. One wave per 8 tokens, lane e = expert e.
template<int NPART>
__global__ void router_post(const float* __restrict__ plg, float* __restrict__ out) {
    __shared__ float s_ent, s_conf, s_cnt[NEXP];
    const int tid  = threadIdx.x;
    const int lane = tid & 63;
    const int wv   = tid >> 6;
    if (tid == 0) { s_ent = 0.f; s_conf = 0.f; }
    if (tid < NEXP) s_cnt[tid] = 0.f;
    __syncthreads();

    const int tb = blockIdx.x * 32 + wv * 8;
    float entA = 0.f, confA = 0.f;

    for (int k = 0; k < 8; ++k) {
        const int t = tb + k;
        float lgv = 0.f;
        #pragma unroll
        for (int p = 0; p < NPART; ++p)
            lgv += plg[(size_t)p * PLG_STRIDE + (size_t)t * 64 + lane];

        float m1 = lgv, m2 = -INFINITY;
        int   i1 = lane, i2 = 127;
        #pragma unroll
        for (int off = 32; off >= 1; off >>= 1) {
            float om1 = __shfl_xor(m1, off);
            int   oi1 = __shfl_xor(i1, off);
            float om2 = __shfl_xor(m2, off);
            int   oi2 = __shfl_xor(i2, off);
            merge2(m1, i1, m2, i2, om1, oi1, om2, oi2);
        }
        float d  = lgv - m1;
        float ex = __expf(d);
        float ss = ex, ts = d * ex;
        #pragma unroll
        for (int off = 32; off >= 1; off >>= 1) {
            ss += __shfl_xor(ss, off);
            ts += __shfl_xor(ts, off);
        }
        float rs = 1.0f / ss;
        out[OFF_P + (size_t)t * 64 + lane] = ex * rs;
        if (lane == 0) {
            float H  = logf(ss) - ts * rs;
            float e2 = __expf(m2 - m1);
            float rn = 1.0f / (1.0f + e2);
            *(float2*)&out[OFF_W + 2 * t] = make_float2(rn, e2 * rn);
            *(float2*)&out[OFF_I + 2 * t] = make_float2((float)i1, (float)i2);
            entA  += H;
            confA += rn;
            atomicAdd(&s_cnt[i1], 1.0f);
            atomicAdd(&s_cnt[i2], 1.0f);
        }
    }
    if (lane == 0) { atomicAdd(&s_ent, entA); atomicAdd(&s_conf, confA); }
    __syncthreads();
    if (tid == 0) {
        atomicAdd(&out[OFF_ENT],  s_ent  * (1.0f / 16384.0f));
        atomicAdd(&out[OFF_CONF], s_conf * (1.0f / 16384.0f));
    }
    if (tid < NEXP)
        atomicAdd(&out[OFF_UTIL + tid], s_cnt[tid] * (1.0f / 32768.0f));
}

extern "C" void kernel_launch(void* const* d_in, const int* in_sizes, int n_in,
                              void* d_out, int out_size, void* d_ws, size_t ws_size,
                              hipStream_t stream) {
    const float* x  = (const float*)d_in[0];
    const float* Wg = (const float*)d_in[1];
    float* out = (float*)d_out;
    float* plg = (float*)d_ws + PLG_OFF;
    (void)in_sizes; (void)n_in; (void)out_size;

    router_wsplit<<<dim3(256), dim3(64), 0, stream>>>(Wg, (uint4*)d_ws, out);
    if (ws_size >= WS_NEED_STRIDED) {
        router_main<true><<<dim3((NTOK / BTOK) * KG), dim3(256), 0, stream>>>(
            x, (const uint4*)d_ws, plg);
        router_post<KG><<<dim3(512), dim3(256), 0, stream>>>(plg, out);
    } else {
        router_zero<<<dim3(1024), dim3(256), 0, stream>>>(plg);
        router_main<false><<<dim3((NTOK / BTOK) * KG), dim3(256), 0, stream>>>(
            x, (const uint4*)d_ws, plg);
        router_post<1><<<dim3(512), dim3(256), 0, stream>>>(plg, out);
    }
}

// Round 8
// 236.831 us; speedup vs baseline: 1.0261x; 1.0261x over previous
//
#include <hip/hip_runtime.h>
#include <math.h>

#define NTOK 16384
#define DIM 2048
#define NEXP 64
#define WTOK 32            // tokens per block (all 4 waves share them)
#define NCW 16             // chunks of 32 per wave (K-slice 512; 4 waves cover 2048)

// flat output offsets (return order)
#define OFF_W    0
#define OFF_I    32768
#define OFF_P    65536
#define OFF_ENT  1114112
#define OFF_CONF 1114113
#define OFF_UTIL 1114114

typedef short s16x8 __attribute__((ext_vector_type(8)));
typedef float f32x4 __attribute__((ext_vector_type(4)));

__device__ __forceinline__ unsigned short f2bf(float v) {
    unsigned u = __builtin_bit_cast(unsigned, v);
    u = u + 0x7FFFu + ((u >> 16) & 1u);          // RNE
    return (unsigned short)(u >> 16);
}
__device__ __forceinline__ float bf2f(unsigned short b) {
    return __builtin_bit_cast(float, (unsigned)b << 16);
}

// async 16B global->LDS (dest = wave-uniform base + lane*16, tracked by vmcnt)
__device__ __forceinline__ void gload16(const void* g, void* l) {
    __builtin_amdgcn_global_load_lds(
        (const __attribute__((address_space(1))) unsigned int*)g,
        (__attribute__((address_space(3))) unsigned int*)l, 16, 0, 0);
}

// zero the 66 stat accumulators (ENT, CONF, UTIL[64])
__global__ void router_init(float* __restrict__ out) {
    if (threadIdx.x < 66) out[OFF_ENT + threadIdx.x] = 0.0f;
}

// ---- x staging (identical to the r5/r6 verified pattern, WTOK=32) ----
// stage chunk c_ of this wave's 32 tokens into ring[wv][c_&1] (4 async 1KB ops).
// XOR swizzle on the GLOBAL source (LDS dest linear, rule #21): LDS 32B-granule
// slot s of token tau holds global granule s ^ (tau&3).
#define STAGE(c_) do { _Pragma("unroll")                                 \
    for (int i_ = 0; i_ < 4; ++i_) {                                     \
        const int tau_ = 8 * i_ + (l >> 3);                              \
        const int gs_  = ((l & 7) >> 1) ^ (tau_ & 3);                    \
        gload16(xw + (size_t)tau_ * DIM + (c_) * 32 + gs_ * 8 + (l & 1) * 4, \
                &ring[wv][(c_) & 1][8 * i_][0]);                         \
    } } while (0)

// exact truncation split of x: 8 fp32 -> 3 bf16 frags (verified math)
#define CONVA3(a0_, a1_) do {                                            \
    float xv[8];                                                         \
    xv[0]=a0_.x; xv[1]=a0_.y; xv[2]=a0_.z; xv[3]=a0_.w;                  \
    xv[4]=a1_.x; xv[5]=a1_.y; xv[6]=a1_.z; xv[7]=a1_.w;                  \
    _Pragma("unroll")                                                    \
    for (int j = 0; j < 8; ++j) {                                        \
        unsigned u_  = __builtin_bit_cast(unsigned, xv[j]);              \
        unsigned hb_ = u_ & 0xFFFF0000u;                                 \
        float    r_  = xv[j] - __builtin_bit_cast(float, hb_);           \
        unsigned mb_ = __builtin_bit_cast(unsigned, r_) & 0xFFFF0000u;   \
        float    r2_ = r_ - __builtin_bit_cast(float, mb_);              \
        unsigned lb_ = __builtin_bit_cast(unsigned, r2_);                \
        ah[j] = (short)(hb_ >> 16);                                      \
        am[j] = (short)(mb_ >> 16);                                      \
        al[j] = (short)(lb_ >> 16);                                      \
    } } while (0)

// read A-frag for token-tile tt_ (0/1) from ring, convert to 3 bf16 frags
#define READA(tt_, c_) do {                                              \
    const int tau_ = (tt_) * 16 + tr;                                    \
    const int sl_  = qd ^ (tau_ & 3);                                    \
    const uint4* row_ = &ring[wv][(c_) & 1][tau_][0];                    \
    float4 a0_ = __builtin_bit_cast(float4, row_[2 * sl_]);              \
    float4 a1_ = __builtin_bit_cast(float4, row_[2 * sl_ + 1]);          \
    CONVA3(a0_, a1_);                                                    \
    } while (0)

// ---- W handling: fp32 direct load + in-register RNE split (== old wsplit) ----
// lane's B-fragment element j for ntile nt, chunk c:
//   W[16nt + tr][wv*512 + 32c + 8qd + j]   (same fragment map as verified)
#define LOADWF(W_, c_) do { _Pragma("unroll")                            \
    for (int nt_ = 0; nt_ < 4; ++nt_) {                                  \
        const float* p_ = wsrc + (size_t)nt_ * 16 * DIM + (c_) * 32;     \
        W_[2 * nt_]     = *(const float4*)(p_);                          \
        W_[2 * nt_ + 1] = *(const float4*)(p_ + 4);                      \
    } } while (0)

// RNE 3-way split of one ntile's 8 fp32 W elems (bit-identical to router_wsplit)
#define CONVW(a_, b_, BH_, BM_, BL_) do {                                \
    float wv8[8];                                                        \
    wv8[0]=a_.x; wv8[1]=a_.y; wv8[2]=a_.z; wv8[3]=a_.w;                  \
    wv8[4]=b_.x; wv8[5]=b_.y; wv8[6]=b_.z; wv8[7]=b_.w;                  \
    _Pragma("unroll")                                                    \
    for (int j = 0; j < 8; ++j) {                                        \
        unsigned short h_ = f2bf(wv8[j]);                                \
        float r_  = wv8[j] - bf2f(h_);                                   \
        unsigned short m_ = f2bf(r_);                                    \
        float r2_ = r_ - bf2f(m_);                                       \
        unsigned short lo_ = f2bf(r2_);                                  \
        BH_[j] = (short)h_; BM_[j] = (short)m_; BL_[j] = (short)lo_;     \
    } } while (0)

#define MF(A_, B_, C_) __builtin_amdgcn_mfma_f32_16x16x32_bf16(A_, B_, C_, 0, 0, 0)

#define PR4(F_, B_, Q0_, Q1_, Q2_, Q3_) do {                             \
    Q0_ = MF(F_, B_[0], Q0_);                                            \
    Q1_ = MF(F_, B_[1], Q1_);                                            \
    Q2_ = MF(F_, B_[2], Q2_);                                            \
    Q3_ = MF(F_, B_[3], Q3_); } while (0)

// 24 MFMAs: 4 ntiles x 6 products {hh,mh,hm,mm,hl,lh} (verified per-acc order)
#define COMPUTE24(Q0_, Q1_, Q2_, Q3_) do {                               \
    PR4(ah, bh, Q0_, Q1_, Q2_, Q3_);                                     \
    PR4(am, bh, Q0_, Q1_, Q2_, Q3_);                                     \
    PR4(ah, bm, Q0_, Q1_, Q2_, Q3_);                                     \
    PR4(am, bm, Q0_, Q1_, Q2_, Q3_);                                     \
    PR4(ah, bl, Q0_, Q1_, Q2_, Q3_);                                     \
    PR4(al, bh, Q0_, Q1_, Q2_, Q3_); } while (0)

// tie-aware top-2 merge (lowest index wins ties — matches serial ascending scan)
__device__ __forceinline__ void merge2(float& m1, int& i1, float& m2, int& i2,
                                       float om1, int oi1, float om2, int oi2) {
    bool of = (om1 > m1) || (om1 == m1 && oi1 < i1);
    float n1, n2; int j1, j2;
    if (of) {
        n1 = om1; j1 = oi1;
        bool s = (m1 > om2) || (m1 == om2 && i1 < oi2);
        n2 = s ? m1 : om2; j2 = s ? i1 : oi2;
    } else {
        n1 = m1; j1 = i1;
        bool s = (om1 > m2) || (om1 == m2 && oi1 < i2);
        n2 = s ? om1 : m2; j2 = s ? oi1 : i2;
    }
    m1 = n1; i1 = j1; m2 = n2; i2 = j2;
}

// ONE kernel, ZERO workspace. 256 threads = 4 independent waves.
// wave wv = 32 tokens x 64 experts x K-slice [wv*512, wv*512+512).
// Barrier-free K-loop (per-wave private ring); deterministic in-block combine
// (g0+g1+g2+g3 ascending = r3's association); in-block wave-parallel post.
__global__ __launch_bounds__(256, 2) void router_main(
    const float* __restrict__ x, const float* __restrict__ Wg,
    float* __restrict__ out)
{
    __shared__ __align__(16) uint4 ring[4][2][WTOK][8];   // 32KB
    __shared__ float lg[WTOK][NEXP + 1];                  // 8.3KB
    __shared__ float s_ent, s_conf, s_cnt[NEXP];

    const int tid = threadIdx.x;
    const int l   = tid & 63;
    const int wv  = tid >> 6;               // wave = K-group 0..3
    const int tr  = l & 15;                 // token row / expert col in tile
    const int qd  = l >> 4;                 // K-octet 0..3
    const int t0  = blockIdx.x * WTOK;

    if (tid == 0) { s_ent = 0.f; s_conf = 0.f; }
    if (tid < NEXP) s_cnt[tid] = 0.f;

    const float* xw   = x  + (size_t)t0 * DIM + wv * (NCW * 32);
    const float* wsrc = Wg + (size_t)tr * DIM + wv * (NCW * 32) + 8 * qd;

    f32x4 q00 = (f32x4)(0.f), q01 = (f32x4)(0.f), q02 = (f32x4)(0.f), q03 = (f32x4)(0.f);
    f32x4 q10 = (f32x4)(0.f), q11 = (f32x4)(0.f), q12 = (f32x4)(0.f), q13 = (f32x4)(0.f);
    s16x8 ah, am, al;
    s16x8 bh[4], bm[4], bl[4];
    float4 wA[8], wB[8];

    // prologue: stage chunk 0 (4 vmem), W fp32 chunks 0,1 (8 vmem each)
    STAGE(0);
    LOADWF(wA, 0); LOADWF(wB, 1);

    // per phase c: STAGE(c+1) [4 ops]; wait so that stage(c) AND W(c) are done:
    //   steady state outstanding-newer = W(c+1) [8] + stage(c+1) [4] = 12;
    //   last phase: nothing newer -> vmcnt(0).  Then 2 tiles x 24 MFMA; W(c+2).
    #pragma unroll
    for (int c = 0; c < NCW; ++c) {
        if (c + 1 < NCW) STAGE(c + 1);
        if (c == NCW - 1) { asm volatile("s_waitcnt vmcnt(0)" ::: "memory"); }
        else              { asm volatile("s_waitcnt vmcnt(12)" ::: "memory"); }
        __builtin_amdgcn_sched_barrier(0);
        {   // split this chunk's W (identical RNE math to old router_wsplit)
            float4* wc = (c & 1) ? wB : wA;
            #pragma unroll
            for (int nt = 0; nt < 4; ++nt)
                CONVW(wc[2 * nt], wc[2 * nt + 1], bh[nt], bm[nt], bl[nt]);
        }
        READA(0, c);
        COMPUTE24(q00, q01, q02, q03);
        READA(1, c);
        COMPUTE24(q10, q11, q12, q13);
        {   // refill the just-consumed W buffer (natural WAR order)
            float4* wn = (c & 1) ? wB : wA;
            if (c + 2 < NCW) LOADWF(wn, c + 2);
        }
    }

    // deterministic combine: lg = g0, then += g1, += g2, += g3 (ascending).
    // C/D layout (verified): col = tr (expert-in-ntile), row = 4*qd + r (token)
#define WRROWS(op_) { _Pragma("unroll")                                  \
    for (int r = 0; r < 4; ++r) {                                        \
        lg[4 * qd + r][0 * 16 + tr]      op_ q00[r];                     \
        lg[4 * qd + r][1 * 16 + tr]      op_ q01[r];                     \
        lg[4 * qd + r][2 * 16 + tr]      op_ q02[r];                     \
        lg[4 * qd + r][3 * 16 + tr]      op_ q03[r];                     \
        lg[16 + 4 * qd + r][0 * 16 + tr] op_ q10[r];                     \
        lg[16 + 4 * qd + r][1 * 16 + tr] op_ q11[r];                     \
        lg[16 + 4 * qd + r][2 * 16 + tr] op_ q12[r];                     \
        lg[16 + 4 * qd + r][3 * 16 + tr] op_ q13[r];                     \
    } }
    if (wv == 0) WRROWS(=);
    __syncthreads();
    if (wv == 1) WRROWS(+=);
    __syncthreads();
    if (wv == 2) WRROWS(+=);
    __syncthreads();
    if (wv == 3) WRROWS(+=);
    __syncthreads();
#undef WRROWS

    // post: 4 waves x 8 tokens; lane = expert. top-2 + softmax + stats.
    float entA = 0.f, confA = 0.f;
    #pragma unroll
    for (int k = 0; k < 8; ++k) {
        const int t = wv * 8 + k;
        float lgv = lg[t][l];

        float m1 = lgv, m2 = -INFINITY;
        int   i1 = l, i2 = 127;
        #pragma unroll
        for (int off = 32; off >= 1; off >>= 1) {
            float om1 = __shfl_xor(m1, off);
            int   oi1 = __shfl_xor(i1, off);
            float om2 = __shfl_xor(m2, off);
            int   oi2 = __shfl_xor(i2, off);
            merge2(m1, i1, m2, i2, om1, oi1, om2, oi2);
        }
        float d  = lgv - m1;
        float ex = __expf(d);
        float ss = ex, ts = d * ex;
        #pragma unroll
        for (int off = 32; off >= 1; off >>= 1) {
            ss += __shfl_xor(ss, off);
            ts += __shfl_xor(ts, off);
        }
        float rs = 1.0f / ss;
        out[OFF_P + (size_t)(t0 + t) * NEXP + l] = ex * rs;
        if (l == 0) {
            float H  = logf(ss) - ts * rs;   // H = ln(s) - (sum d e^d)/s
            float e2 = __expf(m2 - m1);
            float rn = 1.0f / (1.0f + e2);
            *(float2*)&out[OFF_W + 2 * (t0 + t)] = make_float2(rn, e2 * rn);
            *(float2*)&out[OFF_I + 2 * (t0 + t)] = make_float2((float)i1, (float)i2);
            entA  += H;
            confA += rn;
            atomicAdd(&s_cnt[i1], 1.0f);
            atomicAdd(&s_cnt[i2], 1.0f);
        }
    }
    if (l == 0) { atomicAdd(&s_ent, entA); atomicAdd(&s_conf, confA); }
    __syncthreads();

    // stats: pre-scaled so the atomic sums are exact / final means
    if (tid == 0) {
        atomicAdd(&out[OFF_ENT],  s_ent  * (1.0f / 16384.0f));
        atomicAdd(&out[OFF_CONF], s_conf * (1.0f / 16384.0f));
    }
    if (tid < NEXP)
        atomicAdd(&out[OFF_UTIL + tid], s_cnt[tid] * (1.0f / 32768.0f));
}

extern "C" void kernel_launch(void* const* d_in, const int* in_sizes, int n_in,
                              void* d_out, int out_size, void* d_ws, size_t ws_size,
                              hipStream_t stream) {
    const float* x  = (const float*)d_in[0];
    const float* Wg = (const float*)d_in[1];
    float* out = (float*)d_out;
    (void)in_sizes; (void)n_in; (void)out_size; (void)d_ws; (void)ws_size;

    router_init<<<dim3(1), dim3(128), 0, stream>>>(out);
    router_main<<<dim3(NTOK / WTOK), dim3(256), 0, stream>>>(x, Wg, out);
}

// Round 9
// 225.155 us; speedup vs baseline: 1.0793x; 1.0519x over previous
//
#include <hip/hip_runtime.h>
#include <math.h>

#define NTOK 16384
#define DIM 2048
#define NEXP 64
#define WTOK 32            // tokens per block (all 4 waves share them)
#define NCW 16             // chunks of 32 per wave (K-slice 512; 4 waves cover 2048)

// flat output offsets (return order)
#define OFF_W    0
#define OFF_I    32768
#define OFF_P    65536
#define OFF_ENT  1114112
#define OFF_CONF 1114113
#define OFF_UTIL 1114114

typedef short s16x8 __attribute__((ext_vector_type(8)));
typedef float f32x4 __attribute__((ext_vector_type(4)));

__device__ __forceinline__ unsigned short f2bf(float v) {
    unsigned u = __builtin_bit_cast(unsigned, v);
    u = u + 0x7FFFu + ((u >> 16) & 1u);          // RNE
    return (unsigned short)(u >> 16);
}
__device__ __forceinline__ float bf2f(unsigned short b) {
    return __builtin_bit_cast(float, (unsigned)b << 16);
}

// async 16B global->LDS (dest = wave-uniform base + lane*16, tracked by vmcnt)
__device__ __forceinline__ void gload16(const void* g, void* l) {
    __builtin_amdgcn_global_load_lds(
        (const __attribute__((address_space(1))) unsigned int*)g,
        (__attribute__((address_space(3))) unsigned int*)l, 16, 0, 0);
}

// Split W into 3 bf16 planes (hi/mid/lo), fragment-linear (verified r1-r6):
// plane p, chunk c, ntile nt, lane l -> uint4 at wsp[p*16384 + c*256 + nt*64 + l]
// fragment element j: W[16nt + (l&15)][32c + 8*(l>>4) + j]
// Also zeroes the 66 stat accumulators (ENT, CONF, UTIL[64]).
__global__ void router_wsplit(const float* __restrict__ Wg, uint4* __restrict__ wsp,
                              float* __restrict__ out) {
    const int bid = blockIdx.x;
    const int tid = threadIdx.x;
    const int c   = bid >> 2;
    const int gt  = (bid & 3) * 64 + tid;   // 0..255 within chunk
    if (c == 0 && gt < 66) out[OFF_ENT + gt] = 0.0f;
    const int nt = gt >> 6, l = gt & 63;
    const int e  = 16 * nt + (l & 15);
    const int k0 = 32 * c + 8 * (l >> 4);
    const float* src = Wg + (size_t)e * DIM + k0;
    float4 a = *(const float4*)src;
    float4 b = *(const float4*)(src + 4);
    float v[8] = {a.x, a.y, a.z, a.w, b.x, b.y, b.z, b.w};
    unsigned short H[8], M[8], L[8];
    #pragma unroll
    for (int j = 0; j < 8; ++j) {
        H[j] = f2bf(v[j]);  float r = v[j] - bf2f(H[j]);
        M[j] = f2bf(r);     r = r - bf2f(M[j]);
        L[j] = f2bf(r);
    }
    uint4 ph, pm, pl;
    ph.x = H[0] | ((unsigned)H[1] << 16); ph.y = H[2] | ((unsigned)H[3] << 16);
    ph.z = H[4] | ((unsigned)H[5] << 16); ph.w = H[6] | ((unsigned)H[7] << 16);
    pm.x = M[0] | ((unsigned)M[1] << 16); pm.y = M[2] | ((unsigned)M[3] << 16);
    pm.z = M[4] | ((unsigned)M[5] << 16); pm.w = M[6] | ((unsigned)M[7] << 16);
    pl.x = L[0] | ((unsigned)L[1] << 16); pl.y = L[2] | ((unsigned)L[3] << 16);
    pl.z = L[4] | ((unsigned)L[5] << 16); pl.w = L[6] | ((unsigned)L[7] << 16);
    const int idx = c * 256 + gt;
    wsp[idx]         = ph;
    wsp[16384 + idx] = pm;
    wsp[32768 + idx] = pl;
}

// ---- x staging (identical to the r5/r6/r8 verified pattern, WTOK=32) ----
// stage chunk c_ of this wave's 32 tokens into ring[wv][c_&1] (4 async 1KB ops).
// XOR swizzle on the GLOBAL source (LDS dest linear, rule #21): LDS 32B-granule
// slot s of token tau holds global granule s ^ (tau&3).
#define STAGE(c_) do { _Pragma("unroll")                                 \
    for (int i_ = 0; i_ < 4; ++i_) {                                     \
        const int tau_ = 8 * i_ + (l >> 3);                              \
        const int gs_  = ((l & 7) >> 1) ^ (tau_ & 3);                    \
        gload16(xw + (size_t)tau_ * DIM + (c_) * 32 + gs_ * 8 + (l & 1) * 4, \
                &ring[wv][(c_) & 1][8 * i_][0]);                         \
    } } while (0)

// exact truncation split of x: 8 fp32 -> 3 bf16 frags (verified math)
#define CONVA3(a0_, a1_) do {                                            \
    float xv[8];                                                         \
    xv[0]=a0_.x; xv[1]=a0_.y; xv[2]=a0_.z; xv[3]=a0_.w;                  \
    xv[4]=a1_.x; xv[5]=a1_.y; xv[6]=a1_.z; xv[7]=a1_.w;                  \
    _Pragma("unroll")                                                    \
    for (int j = 0; j < 8; ++j) {                                        \
        unsigned u_  = __builtin_bit_cast(unsigned, xv[j]);              \
        unsigned hb_ = u_ & 0xFFFF0000u;                                 \
        float    r_  = xv[j] - __builtin_bit_cast(float, hb_);           \
        unsigned mb_ = __builtin_bit_cast(unsigned, r_) & 0xFFFF0000u;   \
        float    r2_ = r_ - __builtin_bit_cast(float, mb_);              \
        unsigned lb_ = __builtin_bit_cast(unsigned, r2_);                \
        ah[j] = (short)(hb_ >> 16);                                      \
        am[j] = (short)(mb_ >> 16);                                      \
        al[j] = (short)(lb_ >> 16);                                      \
    } } while (0)

// read A-frag for token-tile tt_ (0/1) from ring, convert to 3 bf16 frags
#define READA(tt_, c_) do {                                              \
    const int tau_ = (tt_) * 16 + tr;                                    \
    const int sl_  = qd ^ (tau_ & 3);                                    \
    const uint4* row_ = &ring[wv][(c_) & 1][tau_][0];                    \
    float4 a0_ = __builtin_bit_cast(float4, row_[2 * sl_]);              \
    float4 a1_ = __builtin_bit_cast(float4, row_[2 * sl_ + 1]);          \
    CONVA3(a0_, a1_);                                                    \
    } while (0)

// W regs: 12 uint4 = 4 ntiles x 3 planes {hi,mid,lo} for one chunk of this
// wave's K-slice (global chunk = wv*NCW + c_)
#define LOADW12(W_, c_) do { const int b_ = (wv * NCW + (c_)) * 256 + l; \
    W_[0] = wq[b_];          W_[1] = wq[b_ + 64];                        \
    W_[2] = wq[b_ + 128];    W_[3] = wq[b_ + 192];                       \
    W_[4] = wq[16384 + b_];       W_[5] = wq[16384 + b_ + 64];           \
    W_[6] = wq[16384 + b_ + 128]; W_[7] = wq[16384 + b_ + 192];          \
    W_[8] = wq[32768 + b_];       W_[9] = wq[32768 + b_ + 64];           \
    W_[10] = wq[32768 + b_ + 128]; W_[11] = wq[32768 + b_ + 192]; } while (0)

#define MF(A_, B_, C_) __builtin_amdgcn_mfma_f32_16x16x32_bf16(A_, B_, C_, 0, 0, 0)
#define BC(q_) __builtin_bit_cast(s16x8, q_)

#define PR4(F_, W_, o_, Q0_, Q1_, Q2_, Q3_) do {                         \
    Q0_ = MF(F_, BC(W_[(o_) + 0]), Q0_);                                 \
    Q1_ = MF(F_, BC(W_[(o_) + 1]), Q1_);                                 \
    Q2_ = MF(F_, BC(W_[(o_) + 2]), Q2_);                                 \
    Q3_ = MF(F_, BC(W_[(o_) + 3]), Q3_); } while (0)

// 24 MFMAs: 4 ntiles x 6 products {hh,mh,hm,mm,hl,lh} (verified per-acc order)
#define COMPUTE24(W_, Q0_, Q1_, Q2_, Q3_) do {                           \
    PR4(ah, W_, 0, Q0_, Q1_, Q2_, Q3_);                                  \
    PR4(am, W_, 0, Q0_, Q1_, Q2_, Q3_);                                  \
    PR4(ah, W_, 4, Q0_, Q1_, Q2_, Q3_);                                  \
    PR4(am, W_, 4, Q0_, Q1_, Q2_, Q3_);                                  \
    PR4(ah, W_, 8, Q0_, Q1_, Q2_, Q3_);                                  \
    PR4(al, W_, 0, Q0_, Q1_, Q2_, Q3_); } while (0)

// tie-aware top-2 merge (lowest index wins ties — matches serial ascending scan)
__device__ __forceinline__ void merge2(float& m1, int& i1, float& m2, int& i2,
                                       float om1, int oi1, float om2, int oi2) {
    bool of = (om1 > m1) || (om1 == m1 && oi1 < i1);
    float n1, n2; int j1, j2;
    if (of) {
        n1 = om1; j1 = oi1;
        bool s = (m1 > om2) || (m1 == om2 && i1 < oi2);
        n2 = s ? m1 : om2; j2 = s ? i1 : oi2;
    } else {
        n1 = m1; j1 = i1;
        bool s = (om1 > m2) || (om1 == m2 && oi1 < i2);
        n2 = s ? om1 : m2; j2 = s ? oi1 : i2;
    }
    m1 = n1; i1 = j1; m2 = n2; i2 = j2;
}

// 256 threads = 4 independent waves (no barriers in the K-loop).
// wave wv = 32 tokens x 64 experts x K-slice [wv*512, wv*512+512), W from
// pre-split bf16 planes (workspace — its poison-fill is unconditional, so
// using it is free). Deterministic in-block combine + fused post (r8 verbatim).
__global__ __launch_bounds__(256, 2) void router_main(
    const float* __restrict__ x, const uint4* __restrict__ wq,
    float* __restrict__ out)
{
    __shared__ __align__(16) uint4 ring[4][2][WTOK][8];   // 32KB
    __shared__ float lg[WTOK][NEXP + 1];                  // 8.3KB
    __shared__ float s_ent, s_conf, s_cnt[NEXP];

    const int tid = threadIdx.x;
    const int l   = tid & 63;
    const int wv  = tid >> 6;               // wave = K-group 0..3
    const int tr  = l & 15;                 // token row / expert col in tile
    const int qd  = l >> 4;                 // K-octet 0..3
    const int t0  = blockIdx.x * WTOK;

    if (tid == 0) { s_ent = 0.f; s_conf = 0.f; }
    if (tid < NEXP) s_cnt[tid] = 0.f;

    const float* xw = x + (size_t)t0 * DIM + wv * (NCW * 32);

    f32x4 q00 = (f32x4)(0.f), q01 = (f32x4)(0.f), q02 = (f32x4)(0.f), q03 = (f32x4)(0.f);
    f32x4 q10 = (f32x4)(0.f), q11 = (f32x4)(0.f), q12 = (f32x4)(0.f), q13 = (f32x4)(0.f);
    s16x8 ah, am, al;
    uint4 wA[12], wB[12];

    // prologue: stage chunk 0 (4 vmem), W plane chunks 0,1 (12 vmem each)
    STAGE(0);
    LOADW12(wA, 0); LOADW12(wB, 1);

    // per phase c: STAGE(c+1) [4 ops]; counted wait to drain stage(c) AND W(c):
    //   newer-than-{stage(c), W(c)} = W(c+1)[12] + stage(c+1)[4] = 16;
    //   last phase: nothing newer -> vmcnt(0) (tail-safe). Then 2 tiles x 24
    //   MFMA; refill the just-consumed W buffer (natural WAR order).
    #pragma unroll
    for (int c = 0; c < NCW; ++c) {
        if (c + 1 < NCW) STAGE(c + 1);
        if (c == NCW - 1) { asm volatile("s_waitcnt vmcnt(0)" ::: "memory"); }
        else              { asm volatile("s_waitcnt vmcnt(16)" ::: "memory"); }
        __builtin_amdgcn_sched_barrier(0);
        {
            uint4* wc = (c & 1) ? wB : wA;
            READA(0, c);
            COMPUTE24(wc, q00, q01, q02, q03);
            READA(1, c);
            COMPUTE24(wc, q10, q11, q12, q13);
            if (c + 2 < NCW) LOADW12(wc, c + 2);
        }
    }

    // deterministic combine: lg = g0, then += g1, += g2, += g3 (ascending).
    // C/D layout (verified): col = tr (expert-in-ntile), row = 4*qd + r (token)
#define WRROWS(op_) { _Pragma("unroll")                                  \
    for (int r = 0; r < 4; ++r) {                                        \
        lg[4 * qd + r][0 * 16 + tr]      op_ q00[r];                     \
        lg[4 * qd + r][1 * 16 + tr]      op_ q01[r];                     \
        lg[4 * qd + r][2 * 16 + tr]      op_ q02[r];                     \
        lg[4 * qd + r][3 * 16 + tr]      op_ q03[r];                     \
        lg[16 + 4 * qd + r][0 * 16 + tr] op_ q10[r];                     \
        lg[16 + 4 * qd + r][1 * 16 + tr] op_ q11[r];                     \
        lg[16 + 4 * qd + r][2 * 16 + tr] op_ q12[r];                     \
        lg[16 + 4 * qd + r][3 * 16 + tr] op_ q13[r];                     \
    } }
    if (wv == 0) WRROWS(=);
    __syncthreads();
    if (wv == 1) WRROWS(+=);
    __syncthreads();
    if (wv == 2) WRROWS(+=);
    __syncthreads();
    if (wv == 3) WRROWS(+=);
    __syncthreads();
#undef WRROWS

    // post: 4 waves x 8 tokens; lane = expert. top-2 + softmax + stats.
    float entA = 0.f, confA = 0.f;
    #pragma unroll
    for (int k = 0; k < 8; ++k) {
        const int t = wv * 8 + k;
        float lgv = lg[t][l];

        float m1 = lgv, m2 = -INFINITY;
        int   i1 = l, i2 = 127;
        #pragma unroll
        for (int off = 32; off >= 1; off >>= 1) {
            float om1 = __shfl_xor(m1, off);
            int   oi1 = __shfl_xor(i1, off);
            float om2 = __shfl_xor(m2, off);
            int   oi2 = __shfl_xor(i2, off);
            merge2(m1, i1, m2, i2, om1, oi1, om2, oi2);
        }
        float d  = lgv - m1;
        float ex = __expf(d);
        float ss = ex, ts = d * ex;
        #pragma unroll
        for (int off = 32; off >= 1; off >>= 1) {
            ss += __shfl_xor(ss, off);
            ts += __shfl_xor(ts, off);
        }
        float rs = 1.0f / ss;
        out[OFF_P + (size_t)(t0 + t) * NEXP + l] = ex * rs;
        if (l == 0) {
            float H  = logf(ss) - ts * rs;   // H = ln(s) - (sum d e^d)/s
            float e2 = __expf(m2 - m1);
            float rn = 1.0f / (1.0f + e2);
            *(float2*)&out[OFF_W + 2 * (t0 + t)] = make_float2(rn, e2 * rn);
            *(float2*)&out[OFF_I + 2 * (t0 + t)] = make_float2((float)i1, (float)i2);
            entA  += H;
            confA += rn;
            atomicAdd(&s_cnt[i1], 1.0f);
            atomicAdd(&s_cnt[i2], 1.0f);
        }
    }
    if (l == 0) { atomicAdd(&s_ent, entA); atomicAdd(&s_conf, confA); }
    __syncthreads();

    // stats: pre-scaled so the atomic sums are exact / final means
    if (tid == 0) {
        atomicAdd(&out[OFF_ENT],  s_ent  * (1.0f / 16384.0f));
        atomicAdd(&out[OFF_CONF], s_conf * (1.0f / 16384.0f));
    }
    if (tid < NEXP)
        atomicAdd(&out[OFF_UTIL + tid], s_cnt[tid] * (1.0f / 32768.0f));
}

extern "C" void kernel_launch(void* const* d_in, const int* in_sizes, int n_in,
                              void* d_out, int out_size, void* d_ws, size_t ws_size,
                              hipStream_t stream) {
    const float* x  = (const float*)d_in[0];
    const float* Wg = (const float*)d_in[1];
    float* out = (float*)d_out;
    (void)in_sizes; (void)n_in; (void)out_size; (void)ws_size;

    router_wsplit<<<dim3(256), dim3(64), 0, stream>>>(Wg, (uint4*)d_ws, out);
    router_main<<<dim3(NTOK / WTOK), dim3(256), 0, stream>>>(
        x, (const uint4*)d_ws, out);
}